// Round 2
// baseline (1066.749 us; speedup 1.0000x reference)
//
#include <hip/hip_runtime.h>
#include <math.h>

// Problem constants (S=8192 tokens, E=64 experts, capacity=256)
#define NTOK 8192
#define NEXP 64
#define CAP  256
#define SEC  (NTOK * NEXP * CAP)   // 134217728 floats per output tensor

typedef float v4f __attribute__((ext_vector_type(4)));  // native vec for nontemporal stores

// ---------------------------------------------------------------------------
// Kernel 1: per-token argmax (first-index tie-break) + softmax value at top1.
// One wave (64 lanes) per token row; lane e holds logit for expert e.
// ---------------------------------------------------------------------------
__global__ __launch_bounds__(256) void k_top1(const float* __restrict__ in,
                                              int* __restrict__ top1,
                                              float* __restrict__ val) {
    int wave = threadIdx.x >> 6;
    int lane = threadIdx.x & 63;
    int s = blockIdx.x * 4 + wave;
    float x = in[s * NEXP + lane];

    // wave argmax with smallest-index tie-break (matches jnp.argmax)
    float bv = x;
    int   bi = lane;
#pragma unroll
    for (int off = 32; off > 0; off >>= 1) {
        float ov = __shfl_xor(bv, off);
        int   oi = __shfl_xor(bi, off);
        if (ov > bv || (ov == bv && oi < bi)) { bv = ov; bi = oi; }
    }
    // softmax denominator (fp32); value at argmax = 1/sum
    float ex = expf(x - bv);
#pragma unroll
    for (int off = 32; off > 0; off >>= 1) ex += __shfl_xor(ex, off);

    if (lane == 0) {
        top1[s] = bi;
        val[s]  = 1.0f / ex;
    }
}

// ---------------------------------------------------------------------------
// Kernel 2: deterministic per-expert exclusive rank (order = token index).
// Single block, 1024 threads = 16 waves. Wave w owns tokens [w*512, w*512+512).
// Lane e keeps the running count for expert e within the chunk. Cross-chunk
// offsets via per-expert exclusive scan of chunk histograms in LDS.
// ---------------------------------------------------------------------------
__global__ __launch_bounds__(1024) void k_rank(const int* __restrict__ top1,
                                               int* __restrict__ rank) {
    __shared__ int localrank[NTOK];      // 32 KB
    __shared__ int hist[16][64];         // 4 KB
    __shared__ int chunkoff[16][64];     // 4 KB

    int tid  = threadIdx.x;
    int w    = tid >> 6;
    int lane = tid & 63;
    int base = w * 512;

    int counter = 0;  // tokens seen in this chunk routed to expert `lane`
    for (int j0 = 0; j0 < 512; j0 += 64) {
        int myidx  = top1[base + j0 + lane];
        int myrank = 0;
        for (int j = 0; j < 64; ++j) {
            int t = __shfl(myidx, j);      // expert of token base+j0+j (uniform)
            int r = __shfl(counter, t);    // its local rank (uniform read)
            if (j == lane) myrank = r;
            counter += (lane == t) ? 1 : 0;
        }
        localrank[base + j0 + lane] = myrank;
    }
    hist[w][lane] = counter;
    __syncthreads();

    if (tid < 64) {  // lane-per-expert exclusive scan over 16 chunks
        int off = 0;
        for (int w2 = 0; w2 < 16; ++w2) {
            chunkoff[w2][tid] = off;
            off += hist[w2][tid];
        }
    }
    __syncthreads();

    for (int s = tid; s < NTOK; s += 1024) {
        int t = top1[s];
        rank[s] = localrank[s] + chunkoff[s >> 9][t];
    }
}

// ---------------------------------------------------------------------------
// Kernel 3: fused zero-fill + scatter. One float4 per thread in EACH output.
// Row s spans 4096 float4s; each wave sits entirely inside one row, so the
// three per-row scalar loads are broadcast/L1 hits. 1 GiB of nontemporal
// dwordx4 stores — this kernel is the HBM-write roofline.
// ---------------------------------------------------------------------------
__global__ __launch_bounds__(256) void k_fill(const int* __restrict__ top1,
                                              const int* __restrict__ rank,
                                              const float* __restrict__ val,
                                              v4f* __restrict__ outc,
                                              v4f* __restrict__ outm) {
    int gid = blockIdx.x * 256 + threadIdx.x;   // float4 index, < SEC/4
    int s = gid >> 12;                          // 4096 float4 per row
    int q4 = (gid & 4095) << 2;                 // float offset of this float4 in row

    int   t = top1[s];
    int   r = rank[s];
    float v = val[s];
    bool keep = (r < CAP);
    int p = t * CAP + r;                        // nonzero float offset within row

    v4f c, m;
    c.x = (keep && p == q4 + 0) ? v : 0.0f;
    c.y = (keep && p == q4 + 1) ? v : 0.0f;
    c.z = (keep && p == q4 + 2) ? v : 0.0f;
    c.w = (keep && p == q4 + 3) ? v : 0.0f;
    m.x = (c.x != 0.0f) ? 1.0f : 0.0f;
    m.y = (c.y != 0.0f) ? 1.0f : 0.0f;
    m.z = (c.z != 0.0f) ? 1.0f : 0.0f;
    m.w = (c.w != 0.0f) ? 1.0f : 0.0f;

    __builtin_nontemporal_store(c, &outc[gid]);
    __builtin_nontemporal_store(m, &outm[gid]);
}

extern "C" void kernel_launch(void* const* d_in, const int* in_sizes, int n_in,
                              void* d_out, int out_size, void* d_ws, size_t ws_size,
                              hipStream_t stream) {
    const float* in = (const float*)d_in[0];

    // workspace layout: top1[8192] int | val[8192] float | rank[8192] int
    int*   top1 = (int*)d_ws;
    float* val  = (float*)((char*)d_ws + NTOK * 4);
    int*   rank = (int*)((char*)d_ws + NTOK * 8);

    float* outc = (float*)d_out;
    float* outm = outc + (size_t)SEC;

    hipLaunchKernelGGL(k_top1, dim3(NTOK / 4), dim3(256), 0, stream, in, top1, val);
    hipLaunchKernelGGL(k_rank, dim3(1), dim3(1024), 0, stream, top1, rank);
    hipLaunchKernelGGL(k_fill, dim3(SEC / 4 / 256), dim3(256), 0, stream,
                       top1, rank, val, (v4f*)outc, (v4f*)outm);
}